// Round 10
// baseline (214.058 us; speedup 1.0000x reference)
//
#include <hip/hip_runtime.h>
#include <hip/hip_bf16.h>
#include <stdint.h>

#define Bb 8
#define Tt 256
#define TCC 768
#define TKV 1024
#define NS 1024
#define NH 16
#define DH 64
#define QK_SCALE 0.125f

typedef short bf16x8 __attribute__((ext_vector_type(8)));
typedef float f32x4 __attribute__((ext_vector_type(4)));
typedef unsigned int u32;

__device__ __forceinline__ unsigned short f2bf(float f) {
  union { float f; uint32_t u; } v; v.f = f;
  uint32_t u = v.u;
  u += 0x7fff + ((u >> 16) & 1);   // round-to-nearest-even
  return (unsigned short)(u >> 16);
}

// async global->LDS, 16B per lane (dest = wave-uniform base + lane*16)
__device__ __forceinline__ void gload16(const unsigned short* g, unsigned short* l) {
  __builtin_amdgcn_global_load_lds(
      (__attribute__((address_space(1))) u32*)g,
      (__attribute__((address_space(3))) u32*)l,
      16, 0, 0);
}

// ---- kernel 1: prep = convert_flat (bid<2048) + transpose_convert (bid>=2048)
__global__ __launch_bounds__(256) void prep(
    const float* __restrict__ x, const float* __restrict__ ck,
    const float* __restrict__ Wq, const float* __restrict__ Wk,
    const float* __restrict__ Wv, const float* __restrict__ Wo,
    const float* __restrict__ cv,
    unsigned short* __restrict__ xb, unsigned short* __restrict__ kbw,
    unsigned short* __restrict__ wqt, unsigned short* __restrict__ wkt,
    unsigned short* __restrict__ wvt, unsigned short* __restrict__ wot,
    unsigned short* __restrict__ vbt) {
  __shared__ float tile[64][65];
  int bid = blockIdx.x, tid = threadIdx.x;
  if (bid < 2048) {                       // streaming conversion
    const int64_t nx4 = (int64_t)Bb * Tt * NS / 4;        // 524288
    const int64_t nk4 = (int64_t)Bb * TCC * NS / 4;       // 1572864
    const int64_t stride = 2048LL * 256;
    for (int64_t t = (int64_t)bid * 256 + tid; t < nx4 + nk4; t += stride) {
      if (t < nx4) {
        float4 v = ((const float4*)x)[t];
        ushort4 o; o.x = f2bf(v.x); o.y = f2bf(v.y); o.z = f2bf(v.z); o.w = f2bf(v.w);
        ((ushort4*)xb)[t] = o;
      } else {
        int64_t e = t - nx4;
        float4 v = ((const float4*)ck)[e];
        ushort4 o; o.x = f2bf(v.x); o.y = f2bf(v.y); o.z = f2bf(v.z); o.w = f2bf(v.w);
        int64_t el = e * 4;
        int64_t b = el / ((int64_t)TCC * NS);
        int64_t rem = el % ((int64_t)TCC * NS);
        int64_t d = b * (int64_t)TKV * NS + rem;          // rows 0..767 of concat K
        ((ushort4*)kbw)[d / 4] = o;
      }
    }
    return;
  }
  int tb = bid - 2048;                    // transpose tiles
  const float* src; unsigned short* dst;
  if (tb < 1024) {                        // 4 weight mats, 16x16 tiles of 64x64
    int mat = tb >> 8, t = tb & 255;
    int tr = t >> 4, tc = t & 15;
    const float* W = (mat == 0) ? Wq : (mat == 1) ? Wk : (mat == 2) ? Wv : Wo;
    unsigned short* Wt = (mat == 0) ? wqt : (mat == 1) ? wkt : (mat == 2) ? wvt : wot;
    src = W + (int64_t)(tr * 64) * 1024 + tc * 64;
    dst = Wt + (int64_t)(tc * 64) * 1024 + tr * 64;
  } else {                                // cache_v: per b, [768][1024] -> [1024][1024] cols 0..767
    int e = tb - 1024;                    // 1536 tiles
    int b = e / 192; int t = e % 192;
    int st = t >> 4, ct = t & 15;
    src = cv + (int64_t)b * TCC * NS + (int64_t)(st * 64) * 1024 + ct * 64;
    dst = vbt + (int64_t)b * NS * TKV + (int64_t)(ct * 64) * 1024 + st * 64;
  }
  for (int e = tid; e < 1024; e += 256) {
    int i = e >> 4, j4 = (e & 15) * 4;
    float4 v = *(const float4*)&src[(int64_t)i * 1024 + j4];
    tile[i][j4] = v.x; tile[i][j4 + 1] = v.y; tile[i][j4 + 2] = v.z; tile[i][j4 + 3] = v.w;
  }
  __syncthreads();
  for (int e = tid; e < 1024; e += 256) {
    int i = e >> 4, j4 = (e & 15) * 4;
    ushort4 o;
    o.x = f2bf(tile[j4][i]); o.y = f2bf(tile[j4 + 1][i]);
    o.z = f2bf(tile[j4 + 2][i]); o.w = f2bf(tile[j4 + 3][i]);
    *(ushort4*)&dst[(int64_t)i * 1024 + j4] = o;
  }
}

// -------- kernel 2/5: bf16 MFMA GEMM, 2-phase dbuf, BK=64, XOR-swizzled LDS --
// MODE 0: BM=64 BN=128, grid 768 (QKV).  MODE 1: BM=64 BN=64, grid 512 (Wo).
template <int MODE>
__global__ __launch_bounds__(256) void gemm_mfma(
    const unsigned short* __restrict__ A,
    const unsigned short* __restrict__ Bt0, const unsigned short* __restrict__ Bt1,
    const unsigned short* __restrict__ Bt2,
    const float* __restrict__ bq, const float* __restrict__ bv,
    const float* __restrict__ bo,
    unsigned short* __restrict__ qb,
    float* __restrict__ okf, float* __restrict__ ovf,
    unsigned short* __restrict__ kb, unsigned short* __restrict__ vbt,
    float* __restrict__ outf) {
  constexpr int BM = 64;
  constexpr int BN = (MODE == 0) ? 128 : 64;
  constexpr int MT = 2;
  constexpr int NTf = BN / 32;
  __shared__ __align__(16) unsigned short As[2][BM * 64];
  __shared__ __align__(16) unsigned short Bs[2][BN * 64];

  int tid = threadIdx.x, lane = tid & 63, w = tid >> 6;
  int lr = lane & 15, hi = lane >> 4;
  int wm = w >> 1, wn = w & 1;

  int bid = blockIdx.x;
  int cpx = gridDim.x >> 3;
  int logical = (bid & 7) * cpx + (bid >> 3);   // XCD swizzle (grid % 8 == 0)

  int tm = logical & 31;
  int tn = logical >> 5;
  int seg, col0;
  const unsigned short* Bt;
  if (MODE == 0) {
    seg = tn >> 3; col0 = (tn & 7) * 128;
    Bt = (seg == 0) ? Bt0 : (seg == 1) ? Bt1 : Bt2;
  } else {
    seg = 0; col0 = tn * 64;
    Bt = Bt0;
  }
  int m0 = tm * 64;

  int srow = lane >> 3;
  int sch8 = (((lane & 7) ^ srow)) * 8;
  int sw = lr & 7;

  f32x4 acc[MT][NTf];
#pragma unroll
  for (int i = 0; i < MT; i++)
#pragma unroll
    for (int j = 0; j < NTf; j++) acc[i][j] = (f32x4){0.f, 0.f, 0.f, 0.f};

  auto STAGE = [&](int buf, int k0) {
#pragma unroll
    for (int i = 0; i < 2; i++) {
      int rb = w * 16 + i * 8;
      gload16(&A[(int64_t)(m0 + rb + srow) * 1024 + k0 + sch8], &As[buf][rb * 64]);
    }
#pragma unroll
    for (int i = 0; i < BN / 32; i++) {
      int rb = w * (BN / 4) + i * 8;
      gload16(&Bt[(int64_t)(col0 + rb + srow) * 1024 + k0 + sch8], &Bs[buf][rb * 64]);
    }
  };

  STAGE(0, 0);
  __syncthreads();
  int cur = 0;
  for (int step = 0; step < 16; ++step) {
    if (step < 15) STAGE(cur ^ 1, (step + 1) * 64);
    bf16x8 af[2][MT], bfr[2][NTf];
#pragma unroll
    for (int kk = 0; kk < 2; kk++) {
      int ch = ((kk * 4 + hi) ^ sw) * 8;
#pragma unroll
      for (int mt = 0; mt < MT; mt++)
        af[kk][mt] = *(const bf16x8*)&As[cur][(wm * 32 + mt * 16 + lr) * 64 + ch];
#pragma unroll
      for (int nt = 0; nt < NTf; nt++)
        bfr[kk][nt] = *(const bf16x8*)&Bs[cur][(wn * (BN / 2) + nt * 16 + lr) * 64 + ch];
    }
#pragma unroll
    for (int kk = 0; kk < 2; kk++)
#pragma unroll
      for (int mt = 0; mt < MT; mt++)
#pragma unroll
        for (int nt = 0; nt < NTf; nt++)
          acc[mt][nt] = __builtin_amdgcn_mfma_f32_16x16x32_bf16(af[kk][mt], bfr[kk][nt],
                                                               acc[mt][nt], 0, 0, 0);
    __syncthreads();
    cur ^= 1;
  }

#pragma unroll
  for (int mt = 0; mt < MT; mt++)
#pragma unroll
    for (int nt = 0; nt < NTf; nt++) {
      int row = m0 + wm * 32 + mt * 16 + hi * 4;
      int col = col0 + wn * (BN / 2) + nt * 16 + lr;
      if (MODE == 1) {
        float bias = bo[col];
#pragma unroll
        for (int r = 0; r < 4; r++)
          outf[(int64_t)(row + r) * 1024 + col] = acc[mt][nt][r] + bias;
      } else if (seg == 0) {
        float bias = bq[col];
#pragma unroll
        for (int r = 0; r < 4; r++)
          qb[(int64_t)(row + r) * 1024 + col] = f2bf((acc[mt][nt][r] + bias) * QK_SCALE);
      } else if (seg == 1) {
#pragma unroll
        for (int r = 0; r < 4; r++) {
          float v = acc[mt][nt][r];
          okf[(int64_t)(row + r) * 1024 + col] = v;
          int b = (row + r) >> 8, t = (row + r) & 255;
          kb[((int64_t)(b * TKV + TCC + t)) * 1024 + col] = f2bf(v);
        }
      } else {
        float bias = bv[col];
        int b = row >> 8, t0 = row & 255;
        int64_t voff = ((int64_t)(b * NH + (col >> 6)) * DH + (col & 63)) * TKV + TCC + t0;
        float v0 = acc[mt][nt][0] + bias, v1 = acc[mt][nt][1] + bias,
              v2 = acc[mt][nt][2] + bias, v3 = acc[mt][nt][3] + bias;
        ovf[(int64_t)(row + 0) * 1024 + col] = v0;
        ovf[(int64_t)(row + 1) * 1024 + col] = v1;
        ovf[(int64_t)(row + 2) * 1024 + col] = v2;
        ovf[(int64_t)(row + 3) * 1024 + col] = v3;
        ushort4 pk; pk.x = f2bf(v0); pk.y = f2bf(v1); pk.z = f2bf(v2); pk.w = f2bf(v3);
        *(ushort4*)&vbt[voff] = pk;
      }
    }
}

// ------- kernel 3: flash attention, KV-split x2, unnormalized partials -------
// grid 1024 = B*H*4(qt)*2(s); block 256 = 4 waves x 16 q-rows; 8 chunks of 64.
__global__ __launch_bounds__(256) void attn(
    const unsigned short* __restrict__ qb, const unsigned short* __restrict__ kb,
    const unsigned short* __restrict__ vbt, const float* __restrict__ mask,
    float* __restrict__ Op, float* __restrict__ Mp, float* __restrict__ Lp) {
  __shared__ __align__(16) unsigned short Ks[2][64 * 64];   // [kv][d] swizzled
  __shared__ __align__(16) unsigned short Vs[2][64 * 64];   // [d][kv] swizzled
  __shared__ unsigned short Ps[4][16 * 76];                 // wave-private P

  int tid = threadIdx.x, lane = tid & 63, w = tid >> 6;
  int lr = lane & 15, hi = lane >> 4;
  int bid = blockIdx.x;
  int logical = (bid & 7) * 128 + (bid >> 3);               // XCD swizzle (1024%8==0)
  int s = logical & 1;                                      // kv half
  int qt = (logical >> 1) & 3;
  int bh = logical >> 3, b = bh >> 4, h = bh & 15;
  int q0 = qt * 64 + w * 16;
  int kvbase = s * 512;

  const unsigned short* qp = qb + ((int64_t)(b * Tt + q0 + lr)) * 1024 + h * DH + hi * 8;
  bf16x8 aq0 = *(const bf16x8*)qp;
  bf16x8 aq1 = *(const bf16x8*)(qp + 32);

  f32x4 o[4];
#pragma unroll
  for (int nt = 0; nt < 4; nt++) o[nt] = (f32x4){0.f, 0.f, 0.f, 0.f};
  float m[4] = {-1e30f, -1e30f, -1e30f, -1e30f};
  float l[4] = {0.f, 0.f, 0.f, 0.f};

  const unsigned short* kbase = kb + (int64_t)b * TKV * 1024 + h * DH;
  const unsigned short* vbase = vbt + (int64_t)bh * DH * TKV;
  const float* mbase = mask + (int64_t)(q0 + hi * 4) * TKV;

  int srow = lane >> 3;
  int sch8 = ((lane & 7) ^ srow) * 8;
  int sw = lr & 7;

  auto STAGE = [&](int buf, int kv0) {
#pragma unroll
    for (int i = 0; i < 2; i++) {
      int rb = w * 16 + i * 8;
      gload16(&kbase[(int64_t)(kv0 + rb + srow) * 1024 + sch8], &Ks[buf][rb * 64]);
      gload16(&vbase[(int64_t)(rb + srow) * TKV + kv0 + sch8], &Vs[buf][rb * 64]);
    }
  };

  STAGE(0, kvbase);
  __syncthreads();
  int cur = 0;
  for (int c = 0; c < 8; ++c) {
    int kv0 = kvbase + c * 64;
    if (c < 7) STAGE(cur ^ 1, kv0 + 64);

    float mk[4][4];
#pragma unroll
    for (int nt = 0; nt < 4; nt++)
#pragma unroll
      for (int r = 0; r < 4; r++)
        mk[nt][r] = mbase[(int64_t)r * TKV + kv0 + nt * 16 + lr];

    int ch0 = (hi ^ sw) * 8, ch1 = ((hi + 4) ^ sw) * 8;
    f32x4 sc[4];
#pragma unroll
    for (int nt = 0; nt < 4; nt++) {
      int row = (nt * 16 + lr) * 64;
      bf16x8 bk0 = *(const bf16x8*)&Ks[cur][row + ch0];
      bf16x8 bk1 = *(const bf16x8*)&Ks[cur][row + ch1];
      f32x4 z = (f32x4){0.f, 0.f, 0.f, 0.f};
      z = __builtin_amdgcn_mfma_f32_16x16x32_bf16(aq0, bk0, z, 0, 0, 0);
      z = __builtin_amdgcn_mfma_f32_16x16x32_bf16(aq1, bk1, z, 0, 0, 0);
      sc[nt] = z;
    }
#pragma unroll
    for (int nt = 0; nt < 4; nt++)
#pragma unroll
      for (int r = 0; r < 4; r++) sc[nt][r] += mk[nt][r];

    // online softmax with defer-max (T13, THR=8)
    float cm[4];
#pragma unroll
    for (int r = 0; r < 4; r++) {
      cm[r] = fmaxf(fmaxf(sc[0][r], sc[1][r]), fmaxf(sc[2][r], sc[3][r]));
#pragma unroll
      for (int d = 1; d < 16; d <<= 1) cm[r] = fmaxf(cm[r], __shfl_xor(cm[r], d));
    }
#pragma unroll
    for (int r = 0; r < 4; r++) {
      if (cm[r] > m[r] + 8.f) {                 // rescale only on real growth
        float al = __expf(m[r] - cm[r]);
        m[r] = cm[r];
        l[r] *= al;
        o[0][r] *= al; o[1][r] *= al; o[2][r] *= al; o[3][r] *= al;
      }
    }
    float rs[4] = {0.f, 0.f, 0.f, 0.f};
#pragma unroll
    for (int nt = 0; nt < 4; nt++)
#pragma unroll
      for (int r = 0; r < 4; r++) {
        sc[nt][r] = __expf(sc[nt][r] - m[r]);
        rs[r] += sc[nt][r];
      }
#pragma unroll
    for (int r = 0; r < 4; r++) {
#pragma unroll
      for (int d = 1; d < 16; d <<= 1) rs[r] += __shfl_xor(rs[r], d);
      l[r] += rs[r];
    }

    // P -> bf16 via wave-private LDS
#pragma unroll
    for (int nt = 0; nt < 4; nt++)
#pragma unroll
      for (int r = 0; r < 4; r++)
        Ps[w][(hi * 4 + r) * 76 + nt * 16 + lr] = f2bf(sc[nt][r]);
    bf16x8 pa0 = *(const bf16x8*)&Ps[w][lr * 76 + hi * 8];
    bf16x8 pa1 = *(const bf16x8*)&Ps[w][lr * 76 + 32 + hi * 8];

#pragma unroll
    for (int nt = 0; nt < 4; nt++) {
      int row = (nt * 16 + lr) * 64;
      bf16x8 bv0 = *(const bf16x8*)&Vs[cur][row + ch0];
      bf16x8 bv1 = *(const bf16x8*)&Vs[cur][row + ch1];
      o[nt] = __builtin_amdgcn_mfma_f32_16x16x32_bf16(pa0, bv0, o[nt], 0, 0, 0);
      o[nt] = __builtin_amdgcn_mfma_f32_16x16x32_bf16(pa1, bv1, o[nt], 0, 0, 0);
    }
    __syncthreads();
    cur ^= 1;
  }

  // unnormalized partials
  int p = (bh * 4 + qt) * 2 + s;                            // 0..1023
#pragma unroll
  for (int nt = 0; nt < 4; nt++)
#pragma unroll
    for (int r = 0; r < 4; r++) {
      int row = w * 16 + hi * 4 + r, col = nt * 16 + lr;
      Op[(int64_t)p * 4096 + row * 64 + col] = o[nt][r];
    }
  if (lr == 0) {
#pragma unroll
    for (int r = 0; r < 4; r++) {
      int row = w * 16 + hi * 4 + r;
      Mp[p * 64 + row] = m[r];
      Lp[p * 64 + row] = l[r];
    }
  }
}

// ------- kernel 4: merge the two kv-split partials -> wvb (bf16) -------------
__global__ __launch_bounds__(256) void attn_merge(
    const float* __restrict__ Op, const float* __restrict__ Mp,
    const float* __restrict__ Lp, unsigned short* __restrict__ wvb) {
  int t = blockIdx.x * 256 + threadIdx.x;                   // 524288 threads
  int d4 = (t & 15) * 4;
  int row = (t >> 4) & 63;
  int pq = t >> 10;                                         // 0..511
  int qt = pq & 3, bh = pq >> 2;
  int b = bh >> 4, h = bh & 15;
  int p0 = pq * 2, p1 = p0 + 1;
  float m0 = Mp[p0 * 64 + row], m1 = Mp[p1 * 64 + row];
  float l0 = Lp[p0 * 64 + row], l1 = Lp[p1 * 64 + row];
  float M = fmaxf(m0, m1);
  float w0 = __expf(m0 - M), w1 = __expf(m1 - M);
  float inv = 1.f / (l0 * w0 + l1 * w1);
  float4 o0 = *(const float4*)&Op[((int64_t)p0 * 64 + row) * 64 + d4];
  float4 o1 = *(const float4*)&Op[((int64_t)p1 * 64 + row) * 64 + d4];
  ushort4 pk;
  pk.x = f2bf((o0.x * w0 + o1.x * w1) * inv);
  pk.y = f2bf((o0.y * w0 + o1.y * w1) * inv);
  pk.z = f2bf((o0.z * w0 + o1.z * w1) * inv);
  pk.w = f2bf((o0.w * w0 + o1.w * w1) * inv);
  int q = qt * 64 + row;
  *(ushort4*)&wvb[(int64_t)(b * Tt + q) * 1024 + h * DH + d4] = pk;
}

// ---------------------------------------------------------------------------
extern "C" void kernel_launch(void* const* d_in, const int* in_sizes, int n_in,
                              void* d_out, int out_size, void* d_ws, size_t ws_size,
                              hipStream_t stream) {
  const float* x    = (const float*)d_in[0];
  const float* mask = (const float*)d_in[1];
  const float* ck   = (const float*)d_in[2];
  const float* cv   = (const float*)d_in[3];
  const float* Wq   = (const float*)d_in[4];
  const float* bq   = (const float*)d_in[5];
  const float* Wk   = (const float*)d_in[6];
  const float* Wv   = (const float*)d_in[7];
  const float* bv   = (const float*)d_in[8];
  const float* Wo   = (const float*)d_in[9];
  const float* bo   = (const float*)d_in[10];

  const int64_t NT = (int64_t)Bb * Tt * NS;   // 2097152
  float* outp = (float*)d_out;
  float* okf  = outp + NT;
  float* ovf  = outp + 2 * NT;

  char* ws = (char*)d_ws;
  unsigned short* xb  = (unsigned short*)(ws);                       // 4 MB
  unsigned short* wqt = (unsigned short*)(ws + (4LL << 20));         // 2 MB each
  unsigned short* wkt = (unsigned short*)(ws + (6LL << 20));
  unsigned short* wvt = (unsigned short*)(ws + (8LL << 20));
  unsigned short* wot = (unsigned short*)(ws + (10LL << 20));
  unsigned short* qbw = (unsigned short*)(ws + (12LL << 20));        // 4 MB
  unsigned short* kbw = (unsigned short*)(ws + (16LL << 20));        // 16 MB
  unsigned short* vbt = (unsigned short*)(ws + (32LL << 20));        // 16 MB
  unsigned short* wvb = (unsigned short*)(ws + (48LL << 20));        // 4 MB
  float* Op = (float*)(ws + (52LL << 20));                           // 16 MB
  float* Mp = (float*)(ws + (68LL << 20));                           // 256 KB
  float* Lp = (float*)(ws + (69LL << 20));                           // 256 KB

  prep<<<4608, 256, 0, stream>>>(x, ck, Wq, Wk, Wv, Wo, cv,
                                 xb, kbw, wqt, wkt, wvt, wot, vbt);
  gemm_mfma<0><<<768, 256, 0, stream>>>(xb, wqt, wkt, wvt, bq, bv, bo,
                                        qbw, okf, ovf, kbw, vbt, outp);
  attn<<<1024, 256, 0, stream>>>(qbw, kbw, vbt, mask, Op, Mp, Lp);
  attn_merge<<<2048, 256, 0, stream>>>(Op, Mp, Lp, wvb);
  gemm_mfma<1><<<512, 256, 0, stream>>>(wvb, wot, wot, wot, bq, bv, bo,
                                        qbw, okf, ovf, kbw, vbt, outp);
}

// Round 11
// 211.898 us; speedup vs baseline: 1.0102x; 1.0102x over previous
//
#include <hip/hip_runtime.h>
#include <hip/hip_bf16.h>
#include <stdint.h>

#define Bb 8
#define Tt 256
#define TCC 768
#define TKV 1024
#define NS 1024
#define NH 16
#define DH 64
#define QK_SCALE 0.125f

typedef short bf16x8 __attribute__((ext_vector_type(8)));
typedef float f32x4 __attribute__((ext_vector_type(4)));
typedef unsigned int u32;

__device__ __forceinline__ unsigned short f2bf(float f) {
  union { float f; uint32_t u; } v; v.f = f;
  uint32_t u = v.u;
  u += 0x7fff + ((u >> 16) & 1);   // round-to-nearest-even
  return (unsigned short)(u >> 16);
}

// async global->LDS, 16B per lane (dest = wave-uniform base + lane*16)
__device__ __forceinline__ void gload16(const unsigned short* g, unsigned short* l) {
  __builtin_amdgcn_global_load_lds(
      (__attribute__((address_space(1))) u32*)g,
      (__attribute__((address_space(3))) u32*)l,
      16, 0, 0);
}

// ---- kernel 1: prep = convert_flat (bid<2048) + transpose_convert (bid>=2048)
__global__ __launch_bounds__(256) void prep(
    const float* __restrict__ x, const float* __restrict__ ck,
    const float* __restrict__ Wq, const float* __restrict__ Wk,
    const float* __restrict__ Wv, const float* __restrict__ Wo,
    const float* __restrict__ cv,
    unsigned short* __restrict__ xb, unsigned short* __restrict__ kbw,
    unsigned short* __restrict__ wqt, unsigned short* __restrict__ wkt,
    unsigned short* __restrict__ wvt, unsigned short* __restrict__ wot,
    unsigned short* __restrict__ vbt) {
  __shared__ float tile[64][65];
  int bid = blockIdx.x, tid = threadIdx.x;
  if (bid < 2048) {                       // streaming conversion
    const int64_t nx4 = (int64_t)Bb * Tt * NS / 4;        // 524288
    const int64_t nk4 = (int64_t)Bb * TCC * NS / 4;       // 1572864
    const int64_t stride = 2048LL * 256;
    for (int64_t t = (int64_t)bid * 256 + tid; t < nx4 + nk4; t += stride) {
      if (t < nx4) {
        float4 v = ((const float4*)x)[t];
        ushort4 o; o.x = f2bf(v.x); o.y = f2bf(v.y); o.z = f2bf(v.z); o.w = f2bf(v.w);
        ((ushort4*)xb)[t] = o;
      } else {
        int64_t e = t - nx4;
        float4 v = ((const float4*)ck)[e];
        ushort4 o; o.x = f2bf(v.x); o.y = f2bf(v.y); o.z = f2bf(v.z); o.w = f2bf(v.w);
        int64_t el = e * 4;
        int64_t b = el / ((int64_t)TCC * NS);
        int64_t rem = el % ((int64_t)TCC * NS);
        int64_t d = b * (int64_t)TKV * NS + rem;          // rows 0..767 of concat K
        ((ushort4*)kbw)[d / 4] = o;
      }
    }
    return;
  }
  int tb = bid - 2048;                    // transpose tiles
  const float* src; unsigned short* dst;
  if (tb < 1024) {                        // 4 weight mats, 16x16 tiles of 64x64
    int mat = tb >> 8, t = tb & 255;
    int tr = t >> 4, tc = t & 15;
    const float* W = (mat == 0) ? Wq : (mat == 1) ? Wk : (mat == 2) ? Wv : Wo;
    unsigned short* Wt = (mat == 0) ? wqt : (mat == 1) ? wkt : (mat == 2) ? wvt : wot;
    src = W + (int64_t)(tr * 64) * 1024 + tc * 64;
    dst = Wt + (int64_t)(tc * 64) * 1024 + tr * 64;
  } else {                                // cache_v: per b, [768][1024] -> [1024][1024] cols 0..767
    int e = tb - 1024;                    // 1536 tiles
    int b = e / 192; int t = e % 192;
    int st = t >> 4, ct = t & 15;
    src = cv + (int64_t)b * TCC * NS + (int64_t)(st * 64) * 1024 + ct * 64;
    dst = vbt + (int64_t)b * NS * TKV + (int64_t)(ct * 64) * 1024 + st * 64;
  }
  for (int e = tid; e < 1024; e += 256) {
    int i = e >> 4, j4 = (e & 15) * 4;
    float4 v = *(const float4*)&src[(int64_t)i * 1024 + j4];
    tile[i][j4] = v.x; tile[i][j4 + 1] = v.y; tile[i][j4 + 2] = v.z; tile[i][j4 + 3] = v.w;
  }
  __syncthreads();
  for (int e = tid; e < 1024; e += 256) {
    int i = e >> 4, j4 = (e & 15) * 4;
    ushort4 o;
    o.x = f2bf(tile[j4][i]); o.y = f2bf(tile[j4 + 1][i]);
    o.z = f2bf(tile[j4 + 2][i]); o.w = f2bf(tile[j4 + 3][i]);
    *(ushort4*)&dst[(int64_t)i * 1024 + j4] = o;
  }
}

// -- kernel 2/4: bf16 MFMA GEMM, 3-buf depth-2 pipeline, counted vmcnt, BK=64 -
// MODE 0: BM=64 BN=128, grid 768 (QKV).  MODE 1: BM=64 BN=64, grid 512 (Wo).
// One raw s_barrier per K-step; never drains vmcnt to 0 in the loop (T3+T4).
template <int MODE>
__global__ __launch_bounds__(256) void gemm_mfma(
    const unsigned short* __restrict__ A,
    const unsigned short* __restrict__ Bt0, const unsigned short* __restrict__ Bt1,
    const unsigned short* __restrict__ Bt2,
    const float* __restrict__ bq, const float* __restrict__ bv,
    const float* __restrict__ bo,
    unsigned short* __restrict__ qb,
    float* __restrict__ okf, float* __restrict__ ovf,
    unsigned short* __restrict__ kb, unsigned short* __restrict__ vbt,
    float* __restrict__ outf) {
  constexpr int BM = 64;
  constexpr int BN = (MODE == 0) ? 128 : 64;
  constexpr int MT = 2;
  constexpr int NTf = BN / 32;
  __shared__ __align__(16) unsigned short As[3][BM * 64];
  __shared__ __align__(16) unsigned short Bs[3][BN * 64];

  int tid = threadIdx.x, lane = tid & 63, w = tid >> 6;
  int lr = lane & 15, hi = lane >> 4;
  int wm = w >> 1, wn = w & 1;

  int bid = blockIdx.x;
  int cpx = gridDim.x >> 3;
  int logical = (bid & 7) * cpx + (bid >> 3);   // XCD swizzle (grid % 8 == 0)

  int tm = logical & 31;
  int tn = logical >> 5;
  int seg, col0;
  const unsigned short* Bt;
  if (MODE == 0) {
    seg = tn >> 3; col0 = (tn & 7) * 128;
    Bt = (seg == 0) ? Bt0 : (seg == 1) ? Bt1 : Bt2;
  } else {
    seg = 0; col0 = tn * 64;
    Bt = Bt0;
  }
  int m0 = tm * 64;

  int srow = lane >> 3;
  int sch8 = (((lane & 7) ^ srow)) * 8;
  int sw = lr & 7;

  f32x4 acc[MT][NTf];
#pragma unroll
  for (int i = 0; i < MT; i++)
#pragma unroll
    for (int j = 0; j < NTf; j++) acc[i][j] = (f32x4){0.f, 0.f, 0.f, 0.f};

  auto STAGE = [&](int buf, int k0) {
#pragma unroll
    for (int i = 0; i < 2; i++) {
      int rb = w * 16 + i * 8;
      gload16(&A[(int64_t)(m0 + rb + srow) * 1024 + k0 + sch8], &As[buf][rb * 64]);
    }
#pragma unroll
    for (int i = 0; i < BN / 32; i++) {
      int rb = w * (BN / 4) + i * 8;
      gload16(&Bt[(int64_t)(col0 + rb + srow) * 1024 + k0 + sch8], &Bs[buf][rb * 64]);
    }
  };

  STAGE(0, 0);
  STAGE(1, 64);
  int bc = 0;
  for (int step = 0; step < 16; ++step) {
    // wait for oldest stage only (this step's buffer); keep next stage in flight
    if constexpr (MODE == 0) {
      asm volatile("s_waitcnt vmcnt(6)" ::: "memory");
    } else {
      asm volatile("s_waitcnt vmcnt(4)" ::: "memory");
    }
    __builtin_amdgcn_s_barrier();
    __builtin_amdgcn_sched_barrier(0);
    if (step < 14) {
      int bs = bc + 2; if (bs >= 3) bs -= 3;
      STAGE(bs, (step + 2) * 64);
    }
    bf16x8 af[2][MT], bfr[2][NTf];
#pragma unroll
    for (int kk = 0; kk < 2; kk++) {
      int ch = ((kk * 4 + hi) ^ sw) * 8;
#pragma unroll
      for (int mt = 0; mt < MT; mt++)
        af[kk][mt] = *(const bf16x8*)&As[bc][(wm * 32 + mt * 16 + lr) * 64 + ch];
#pragma unroll
      for (int nt = 0; nt < NTf; nt++)
        bfr[kk][nt] = *(const bf16x8*)&Bs[bc][(wn * (BN / 2) + nt * 16 + lr) * 64 + ch];
    }
#pragma unroll
    for (int kk = 0; kk < 2; kk++)
#pragma unroll
      for (int mt = 0; mt < MT; mt++)
#pragma unroll
        for (int nt = 0; nt < NTf; nt++)
          acc[mt][nt] = __builtin_amdgcn_mfma_f32_16x16x32_bf16(af[kk][mt], bfr[kk][nt],
                                                               acc[mt][nt], 0, 0, 0);
    bc = (bc == 2) ? 0 : bc + 1;
  }

#pragma unroll
  for (int mt = 0; mt < MT; mt++)
#pragma unroll
    for (int nt = 0; nt < NTf; nt++) {
      int row = m0 + wm * 32 + mt * 16 + hi * 4;
      int col = col0 + wn * (BN / 2) + nt * 16 + lr;
      if (MODE == 1) {
        float bias = bo[col];
#pragma unroll
        for (int r = 0; r < 4; r++)
          outf[(int64_t)(row + r) * 1024 + col] = acc[mt][nt][r] + bias;
      } else if (seg == 0) {
        float bias = bq[col];
#pragma unroll
        for (int r = 0; r < 4; r++)
          qb[(int64_t)(row + r) * 1024 + col] = f2bf((acc[mt][nt][r] + bias) * QK_SCALE);
      } else if (seg == 1) {
#pragma unroll
        for (int r = 0; r < 4; r++) {
          float v = acc[mt][nt][r];
          okf[(int64_t)(row + r) * 1024 + col] = v;
          int b = (row + r) >> 8, t = (row + r) & 255;
          kb[((int64_t)(b * TKV + TCC + t)) * 1024 + col] = f2bf(v);
        }
      } else {
        float bias = bv[col];
        int b = row >> 8, t0 = row & 255;
        int64_t voff = ((int64_t)(b * NH + (col >> 6)) * DH + (col & 63)) * TKV + TCC + t0;
        float v0 = acc[mt][nt][0] + bias, v1 = acc[mt][nt][1] + bias,
              v2 = acc[mt][nt][2] + bias, v3 = acc[mt][nt][3] + bias;
        ovf[(int64_t)(row + 0) * 1024 + col] = v0;
        ovf[(int64_t)(row + 1) * 1024 + col] = v1;
        ovf[(int64_t)(row + 2) * 1024 + col] = v2;
        ovf[(int64_t)(row + 3) * 1024 + col] = v3;
        ushort4 pk; pk.x = f2bf(v0); pk.y = f2bf(v1); pk.z = f2bf(v2); pk.w = f2bf(v3);
        *(ushort4*)&vbt[voff] = pk;
      }
    }
}

// -- kernel 3: flash attention, 3-buf depth-2 pipeline, counted vmcnt ---------
// grid 512 = B*H*4 qblocks of 64 rows; 4 waves own disjoint 16-row groups; 16
// KV chunks of 64. One raw s_barrier per chunk; mask loads issued BEFORE the
// next stage so their use-wait retires only the old stage (in-order vmcnt).
__global__ __launch_bounds__(256) void attn(
    const unsigned short* __restrict__ qb, const unsigned short* __restrict__ kb,
    const unsigned short* __restrict__ vbt, const float* __restrict__ mask,
    unsigned short* __restrict__ wvb) {
  __shared__ __align__(16) unsigned short Ks[3][64 * 64];   // [kv][d] swizzled
  __shared__ __align__(16) unsigned short Vs[3][64 * 64];   // [d][kv] swizzled
  __shared__ unsigned short Ps[4][16 * 76];                 // wave-private P

  int tid = threadIdx.x, lane = tid & 63, w = tid >> 6;
  int lr = lane & 15, hi = lane >> 4;
  int bid = blockIdx.x;
  int logical = (bid & 7) * 64 + (bid >> 3);                // XCD swizzle (512%8==0)
  int qt = logical & 3, bh = logical >> 2, b = bh >> 4, h = bh & 15;
  int q0 = qt * 64 + w * 16;

  const unsigned short* qp = qb + ((int64_t)(b * Tt + q0 + lr)) * 1024 + h * DH + hi * 8;
  bf16x8 aq0 = *(const bf16x8*)qp;
  bf16x8 aq1 = *(const bf16x8*)(qp + 32);

  f32x4 o[4];
#pragma unroll
  for (int nt = 0; nt < 4; nt++) o[nt] = (f32x4){0.f, 0.f, 0.f, 0.f};
  float m[4] = {-1e30f, -1e30f, -1e30f, -1e30f};
  float l[4] = {0.f, 0.f, 0.f, 0.f};

  const unsigned short* kbase = kb + (int64_t)b * TKV * 1024 + h * DH;
  const unsigned short* vbase = vbt + (int64_t)bh * DH * TKV;
  const float* mbase = mask + (int64_t)(q0 + hi * 4) * TKV;

  int srow = lane >> 3;
  int sch8 = ((lane & 7) ^ srow) * 8;
  int sw = lr & 7;

  auto STAGE = [&](int buf, int kv0) {
#pragma unroll
    for (int i = 0; i < 2; i++) {
      int rb = w * 16 + i * 8;
      gload16(&kbase[(int64_t)(kv0 + rb + srow) * 1024 + sch8], &Ks[buf][rb * 64]);
      gload16(&vbase[(int64_t)(rb + srow) * TKV + kv0 + sch8], &Vs[buf][rb * 64]);
    }
  };

  STAGE(0, 0);
  STAGE(1, 64);
  int bc = 0;
  for (int c = 0; c < 16; ++c) {
    int kv0 = c * 64;
    asm volatile("s_waitcnt vmcnt(4)" ::: "memory");        // this chunk's stage done
    __builtin_amdgcn_s_barrier();
    __builtin_amdgcn_sched_barrier(0);

    // mask prefetch FIRST (older in vmcnt queue than next stage)
    float mk[4][4];
#pragma unroll
    for (int nt = 0; nt < 4; nt++)
#pragma unroll
      for (int r = 0; r < 4; r++)
        mk[nt][r] = mbase[(int64_t)r * TKV + kv0 + nt * 16 + lr];

    if (c < 14) {
      int bs = bc + 2; if (bs >= 3) bs -= 3;
      STAGE(bs, kv0 + 128);
    }

    int ch0 = (hi ^ sw) * 8, ch1 = ((hi + 4) ^ sw) * 8;
    f32x4 sc[4];
#pragma unroll
    for (int nt = 0; nt < 4; nt++) {
      int row = (nt * 16 + lr) * 64;
      bf16x8 bk0 = *(const bf16x8*)&Ks[bc][row + ch0];
      bf16x8 bk1 = *(const bf16x8*)&Ks[bc][row + ch1];
      f32x4 z = (f32x4){0.f, 0.f, 0.f, 0.f};
      z = __builtin_amdgcn_mfma_f32_16x16x32_bf16(aq0, bk0, z, 0, 0, 0);
      z = __builtin_amdgcn_mfma_f32_16x16x32_bf16(aq1, bk1, z, 0, 0, 0);
      sc[nt] = z;
    }
#pragma unroll
    for (int nt = 0; nt < 4; nt++)
#pragma unroll
      for (int r = 0; r < 4; r++) sc[nt][r] += mk[nt][r];

    // online softmax with defer-max (T13, THR=8)
    float cm[4];
#pragma unroll
    for (int r = 0; r < 4; r++) {
      cm[r] = fmaxf(fmaxf(sc[0][r], sc[1][r]), fmaxf(sc[2][r], sc[3][r]));
#pragma unroll
      for (int d = 1; d < 16; d <<= 1) cm[r] = fmaxf(cm[r], __shfl_xor(cm[r], d));
    }
#pragma unroll
    for (int r = 0; r < 4; r++) {
      if (cm[r] > m[r] + 8.f) {                 // rescale only on real growth
        float al = __expf(m[r] - cm[r]);
        m[r] = cm[r];
        l[r] *= al;
        o[0][r] *= al; o[1][r] *= al; o[2][r] *= al; o[3][r] *= al;
      }
    }
    float rs[4] = {0.f, 0.f, 0.f, 0.f};
#pragma unroll
    for (int nt = 0; nt < 4; nt++)
#pragma unroll
      for (int r = 0; r < 4; r++) {
        sc[nt][r] = __expf(sc[nt][r] - m[r]);
        rs[r] += sc[nt][r];
      }
#pragma unroll
    for (int r = 0; r < 4; r++) {
#pragma unroll
      for (int d = 1; d < 16; d <<= 1) rs[r] += __shfl_xor(rs[r], d);
      l[r] += rs[r];
    }

    // P -> bf16 via wave-private LDS (no barrier; compiler inserts lgkm waits)
#pragma unroll
    for (int nt = 0; nt < 4; nt++)
#pragma unroll
      for (int r = 0; r < 4; r++)
        Ps[w][(hi * 4 + r) * 76 + nt * 16 + lr] = f2bf(sc[nt][r]);
    bf16x8 pa0 = *(const bf16x8*)&Ps[w][lr * 76 + hi * 8];
    bf16x8 pa1 = *(const bf16x8*)&Ps[w][lr * 76 + 32 + hi * 8];

#pragma unroll
    for (int nt = 0; nt < 4; nt++) {
      int row = (nt * 16 + lr) * 64;
      bf16x8 bv0 = *(const bf16x8*)&Vs[bc][row + ch0];
      bf16x8 bv1 = *(const bf16x8*)&Vs[bc][row + ch1];
      o[nt] = __builtin_amdgcn_mfma_f32_16x16x32_bf16(pa0, bv0, o[nt], 0, 0, 0);
      o[nt] = __builtin_amdgcn_mfma_f32_16x16x32_bf16(pa1, bv1, o[nt], 0, 0, 0);
    }
    bc = (bc == 2) ? 0 : bc + 1;
  }

  float inv[4];
#pragma unroll
  for (int r = 0; r < 4; r++) inv[r] = 1.f / l[r];
#pragma unroll
  for (int nt = 0; nt < 4; nt++)
#pragma unroll
    for (int r = 0; r < 4; r++)
      wvb[(int64_t)(b * Tt + q0 + hi * 4 + r) * 1024 + h * DH + nt * 16 + lr] =
          f2bf(o[nt][r] * inv[r]);
}

// ---------------------------------------------------------------------------
extern "C" void kernel_launch(void* const* d_in, const int* in_sizes, int n_in,
                              void* d_out, int out_size, void* d_ws, size_t ws_size,
                              hipStream_t stream) {
  const float* x    = (const float*)d_in[0];
  const float* mask = (const float*)d_in[1];
  const float* ck   = (const float*)d_in[2];
  const float* cv   = (const float*)d_in[3];
  const float* Wq   = (const float*)d_in[4];
  const float* bq   = (const float*)d_in[5];
  const float* Wk   = (const float*)d_in[6];
  const float* Wv   = (const float*)d_in[7];
  const float* bv   = (const float*)d_in[8];
  const float* Wo   = (const float*)d_in[9];
  const float* bo   = (const float*)d_in[10];

  const int64_t NT = (int64_t)Bb * Tt * NS;   // 2097152
  float* outp = (float*)d_out;
  float* okf  = outp + NT;
  float* ovf  = outp + 2 * NT;

  char* ws = (char*)d_ws;
  unsigned short* xb  = (unsigned short*)(ws);                       // 4 MB
  unsigned short* wqt = (unsigned short*)(ws + (4LL << 20));         // 2 MB each
  unsigned short* wkt = (unsigned short*)(ws + (6LL << 20));
  unsigned short* wvt = (unsigned short*)(ws + (8LL << 20));
  unsigned short* wot = (unsigned short*)(ws + (10LL << 20));
  unsigned short* qbw = (unsigned short*)(ws + (12LL << 20));        // 4 MB
  unsigned short* kbw = (unsigned short*)(ws + (16LL << 20));        // 16 MB
  unsigned short* vbt = (unsigned short*)(ws + (32LL << 20));        // 16 MB
  unsigned short* wvb = (unsigned short*)(ws + (48LL << 20));        // 4 MB

  prep<<<4608, 256, 0, stream>>>(x, ck, Wq, Wk, Wv, Wo, cv,
                                 xb, kbw, wqt, wkt, wvt, wot, vbt);
  gemm_mfma<0><<<768, 256, 0, stream>>>(xb, wqt, wkt, wvt, bq, bv, bo,
                                        qbw, okf, ovf, kbw, vbt, outp);
  attn<<<512, 256, 0, stream>>>(qbw, kbw, vbt, mask, wvb);
  gemm_mfma<1><<<512, 256, 0, stream>>>(wvb, wot, wot, wot, bq, bv, bo,
                                        qbw, okf, ovf, kbw, vbt, outp);
}